// Round 4
// baseline (915.038 us; speedup 1.0000x reference)
//
#include <hip/hip_runtime.h>

// Correlation volume, N=8, Z=128, H=W=160, 81 shifts (9 dy x 9 dx).
// v4: r1's no-LDS/no-barrier structure with register pipeline deepened from
// distance-1 to distance-3 (ring of 3 named buffers, static indexing).
// 1200 independent 3-wave blocks (dy-triple of a 16x32 tile), XCD-swizzled
// (bid%8 = image so each XCD's L2 holds one image).
#define NB 8
#define ZD 128
#define HD 160
#define WD 160
#define PLANE (HD * WD)            // 25600
#define IMG (ZD * PLANE)

#define TI 16
#define TJ 32
#define TILES_PER_IMG 50           // 10 x 5
#define DQ 3                       // dy-triples per tile -> 3 waves/block
#define NTHREADS 192

// Issue the 6 loads (a: 2x float4, b: 4x float4) for the next z into buffer
// (aa,bb), then advance the running pointers. OOB b-segments -> zero page,
// stride 0.
#define LOADS(aa, bb) do { \
    *(float4*)(&aa[0])  = *(const float4*)(pa); \
    *(float4*)(&aa[4])  = *(const float4*)(pa + 4); \
    *(float4*)(&bb[0])  = *(const float4*)(pb0); \
    *(float4*)(&bb[4])  = *(const float4*)(pb1); \
    *(float4*)(&bb[8])  = *(const float4*)(pb2); \
    *(float4*)(&bb[12]) = *(const float4*)(pb3); \
    pa += PLANE; pb0 += s0; pb1 += s1; pb2 += s2; pb3 += s3; \
} while (0)

#define FMAS(aa, bb) do { \
    _Pragma("unroll") \
    for (int d = 0; d < 9; ++d) { \
        _Pragma("unroll") \
        for (int p = 0; p < 8; ++p) \
            acc[d][p] = fmaf(aa[p], bb[p + d], acc[d][p]); \
    } \
} while (0)

__global__ __launch_bounds__(NTHREADS, 3)
void corr_vol_kernel(const float* __restrict__ A, const float* __restrict__ B,
                     const float* __restrict__ zp, float* __restrict__ out) {
    const int bid = blockIdx.x;
    const int x  = bid & 7;            // XCD = image
    const int s  = bid >> 3;           // 0..149 within XCD
    const int tl = s / DQ;             // tile 0..49
    const int dq = s - DQ * tl;        // dy-triple 0..2
    const int n  = x;
    const int it = tl / 5, jt = tl - 5 * it;
    const int i0 = it * TI, j0 = jt * TJ;

    const int w = dq * 3 + (threadIdx.x >> 6); // dy index 0..8 (this wave's)
    const int l = threadIdx.x & 63;
    const int r = l >> 2;              // pixel row 0..15
    const int g = l & 3;               // col group (8 cols each)

    // A pointer: always in-bounds (tile interior).
    const float* pa = A + (size_t)n * IMG + (size_t)(i0 + r) * WD + (j0 + 8 * g);

    // B descriptors: 4 float4 segments covering cols [j0+8g-4, j0+8g+11],
    // row i0+r+w-4. OOB segment -> zero page, stride 0.
    const int br = i0 + r + w - 4;
    const bool rv = (unsigned)br < (unsigned)HD;
    const float* bbase = B + (size_t)n * IMG + (size_t)br * WD + (j0 + 8 * g - 4);
    const int c0 = j0 + 8 * g - 4;     // col of segment 0 (multiple of 4)

    const float *pb0, *pb1, *pb2, *pb3;
    int s0, s1, s2, s3;
    {
        bool v;
        v = rv && ((unsigned)(c0 +  0) < (unsigned)WD);
        pb0 = v ? bbase +  0 : zp;  s0 = v ? PLANE : 0;
        v = rv && ((unsigned)(c0 +  4) < (unsigned)WD);
        pb1 = v ? bbase +  4 : zp;  s1 = v ? PLANE : 0;
        v = rv && ((unsigned)(c0 +  8) < (unsigned)WD);
        pb2 = v ? bbase +  8 : zp;  s2 = v ? PLANE : 0;
        v = rv && ((unsigned)(c0 + 12) < (unsigned)WD);
        pb3 = v ? bbase + 12 : zp;  s3 = v ? PLANE : 0;
    }

    float acc[9][8];
    #pragma unroll
    for (int d = 0; d < 9; ++d)
        #pragma unroll
        for (int p = 0; p < 8; ++p) acc[d][p] = 0.f;

    // Distance-3 register ring: buffers hold z, z+1, z+2.
    float a0[8], b0[16], a1[8], b1[16], a2[8], b2[16];
    LOADS(a0, b0);                     // z = 0
    LOADS(a1, b1);                     // z = 1
    LOADS(a2, b2);                     // z = 2

    // Main loop: 41 iterations consume z = 0..122, load z = 3..125.
    #pragma unroll 1
    for (int m = 0; m < 41; ++m) {
        FMAS(a0, b0);                  // consume z = 3m
        LOADS(a0, b0);                 // issue   z = 3m+3
        FMAS(a1, b1);                  // consume z = 3m+1
        LOADS(a1, b1);                 // issue   z = 3m+4
        FMAS(a2, b2);                  // consume z = 3m+2
        LOADS(a2, b2);                 // issue   z = 3m+5
    }
    // Tail: bufs hold z = 123,124,125; still need loads for 126,127 only.
    FMAS(a0, b0);                      // z = 123
    LOADS(a0, b0);                     // z = 126
    FMAS(a1, b1);                      // z = 124
    LOADS(a1, b1);                     // z = 127  (last load; max z touched = 127)
    FMAS(a2, b2);                      // z = 125
    FMAS(a0, b0);                      // z = 126
    FMAS(a1, b1);                      // z = 127

    // Epilogue: out[k = d*9 + w]; lanes of a wave cover 16 rows x 32 cols.
    float* obase = out + (((size_t)n * 81) * HD + (i0 + r)) * WD + j0 + 8 * g;
    #pragma unroll
    for (int d = 0; d < 9; ++d) {
        const int kk = d * 9 + w;
        float* o = obase + (size_t)kk * PLANE;
        *(float4*)(&o[0]) = make_float4(acc[d][0], acc[d][1], acc[d][2], acc[d][3]);
        *(float4*)(&o[4]) = make_float4(acc[d][4], acc[d][5], acc[d][6], acc[d][7]);
    }
}

extern "C" void kernel_launch(void* const* d_in, const int* in_sizes, int n_in,
                              void* d_out, int out_size, void* d_ws, size_t ws_size,
                              hipStream_t stream) {
    const float* A = (const float*)d_in[0];
    const float* B = (const float*)d_in[1];
    float* out = (float*)d_out;
    // 256 B zero page for OOB b-segments (d_ws is re-poisoned every launch).
    hipMemsetAsync(d_ws, 0, 256, stream);
    corr_vol_kernel<<<dim3(NB * TILES_PER_IMG * DQ), dim3(NTHREADS), 0, stream>>>(
        A, B, (const float*)d_ws, out);
}

// Round 5
// 315.134 us; speedup vs baseline: 2.9036x; 2.9036x over previous
//
#include <hip/hip_runtime.h>

// Correlation volume, N=8, Z=128, H=W=160, 81 shifts (9 dy x 9 dx).
// v5: r0's proven LDS/vmcnt staging structure, re-gridded for occupancy:
// TI 16->8 => 800 blocks of 9 waves (576 thr) => 3 blocks/CU resident
// (27 waves/CU) and a balanced grid (800 ~= 3.125*256). Per-lane work
// drops to 4 px (acc[9][4] = 36 VGPR, no spill risk). Staging: exactly
// 1 global_load_lds per thread per prefetch, NBUF=4 / distance 3,
// wait vmcnt(2), chunk = ZC=2 z-slices. XCD swizzle: bid%8 = image.
#define NB 8
#define ZD 128
#define HD 160
#define WD 160
#define PLANE (HD * WD)            // 25600
#define IMG (ZD * PLANE)

#define TI 8
#define TJ 32
#define COLT 5                     // col tiles; 20 row tiles -> 100 tiles/img
#define NTHREADS 576               // 9 waves; wave w = dy index
#define ZC 2
#define NCHUNK (ZD / ZC)           // 64

#define ASL 9                      // A 16B-slots/row (8 data + 1 pad)
#define BSL 11                     // B 16B-slots/row (10 data + 1 pad)
#define BROWS 16                   // B row window (8 + 8 halo)
#define A_SLOTS (ZC * TI * ASL)    // 144
#define B_SLOTS (ZC * BROWS * BSL) // 352
#define REAL_SLOTS (A_SLOTS + B_SLOTS) // 496
#define BUF_SLOTS 512              // padded; slots >= 496 are dead pad
#define NBUF 4                     // prefetch distance 3

#define GP(x) ((const __attribute__((address_space(1))) void*)(x))
#define LP(x) ((__attribute__((address_space(3))) void*)(x))

__global__ __launch_bounds__(NTHREADS, 6)
void corr_vol_kernel(const float* __restrict__ A, const float* __restrict__ B,
                     const float* __restrict__ zp, float* __restrict__ out) {
    __shared__ float4 lds[NBUF * BUF_SLOTS];   // 32 KB
    __shared__ float4 dump[64];                // sink for wave-8 / tail dummies

    const int tid = threadIdx.x;
    const int bid = blockIdx.x;
    const int n  = bid & 7;            // XCD = image
    const int s  = bid >> 3;           // tile 0..99
    const int it = s / COLT, jt = s - COLT * it;
    const int i0 = it * TI, j0 = jt * TJ;

    const float* Abase = A + (size_t)n * IMG;
    const float* Bbase = B + (size_t)n * IMG;

    // ---- staging descriptor: slot = tid (A [0,144), B [144,496), pad/dummy) ----
    const float* p; int st;
    if (tid < A_SLOTS) {
        const int zA = tid / (TI * ASL), rem = tid % (TI * ASL);
        const int rA = rem / ASL, cA = rem % ASL;
        const bool v = (cA < 8);
        p = v ? Abase + (size_t)zA * PLANE + (size_t)(i0 + rA) * WD + (j0 + 4 * cA) : zp;
        st = v ? ZC * PLANE : 0;
    } else if (tid < REAL_SLOTS) {
        const int q = tid - A_SLOTS;
        const int zB = q / (BROWS * BSL), rem = q % (BROWS * BSL);
        const int rB = rem / BSL, cB = rem % BSL;
        const int gr = i0 - 4 + rB, gc = j0 - 4 + 4 * cB;
        const bool v = (cB < 10) && ((unsigned)gr < (unsigned)HD) &&
                       ((unsigned)gc < (unsigned)WD);
        p = v ? Bbase + (size_t)zB * PLANE + (size_t)gr * WD + gc : zp;
        st = v ? ZC * PLANE : 0;
    } else {                           // pad slots 496..511 and wave 8
        p = zp; st = 0;
    }
    const bool in_buf = (tid < BUF_SLOTS);            // wave-uniform (512 = 8*64)
    const unsigned dslot = (unsigned)(tid & ~63);     // wave-uniform slot base
    const float* pp = p;

    // Exactly 1 global_load_lds per thread per prefetch -> exact vmcnt math.
    auto prefetch = [&](int k2, int pb) {
        char* base = (char*)&lds[pb * BUF_SLOTS];
        if (k2 < NCHUNK) {
            __builtin_amdgcn_global_load_lds(GP(pp),
                LP(in_buf ? base + 16u * dslot : (char*)&dump[0]), 16, 0, 0);
            pp += st;
        } else {  // tail dummy keeps per-wave outstanding-count uniform
            __builtin_amdgcn_global_load_lds(GP(zp), LP((char*)&dump[0]), 16, 0, 0);
        }
    };

    const int w = tid >> 6;            // dy index 0..8
    const int l = tid & 63;
    const int r = l >> 3;              // pixel row 0..7
    const int g = l & 7;               // col group (4 cols each)

    // LDS float offsets (constant per thread)
    const int aoff = ASL * 4 * r + 4 * g;              // within A z-slice
    const int boff = BSL * 4 * (r + w) + 4 * g;        // within B z-slice

    float acc[9][4];
    #pragma unroll
    for (int d = 0; d < 9; ++d)
        #pragma unroll
        for (int q = 0; q < 4; ++q) acc[d][q] = 0.f;

    prefetch(0, 0);
    prefetch(1, 1);
    prefetch(2, 2);

#define STEP(k, rb, pb) do {                                                    \
    asm volatile("s_waitcnt vmcnt(2)\n\ts_barrier" ::: "memory");               \
    prefetch((k) + 3, (pb));                                                    \
    const float* Af = (const float*)&lds[(rb) * BUF_SLOTS];                     \
    _Pragma("unroll")                                                           \
    for (int z = 0; z < ZC; ++z) {                                              \
        const float* az = Af + z * (TI * ASL * 4) + aoff;                       \
        const float* bz = Af + 4 * A_SLOTS + z * (BROWS * BSL * 4) + boff;      \
        float a[4], b[12];                                                      \
        *(float4*)&a[0] = *(const float4*)(az);                                 \
        *(float4*)&b[0] = *(const float4*)(bz);                                 \
        *(float4*)&b[4] = *(const float4*)(bz + 4);                             \
        *(float4*)&b[8] = *(const float4*)(bz + 8);                             \
        _Pragma("unroll")                                                       \
        for (int d = 0; d < 9; ++d)                                             \
            _Pragma("unroll")                                                   \
            for (int q = 0; q < 4; ++q)                                         \
                acc[d][q] = fmaf(a[q], b[q + d], acc[d][q]);                    \
    }                                                                           \
} while (0)

    for (int m = 0; m < NCHUNK / 4; ++m) {
        const int k = 4 * m;
        STEP(k + 0, 0, 3);
        STEP(k + 1, 1, 0);
        STEP(k + 2, 2, 1);
        STEP(k + 3, 3, 2);
    }
#undef STEP

    asm volatile("s_waitcnt vmcnt(0)" ::: "memory");  // drain tail dummies

    // ---- epilogue: out[k = d*9 + w] (d = x-shift, w = y-shift) ----
    #pragma unroll
    for (int d = 0; d < 9; ++d) {
        const int kk = d * 9 + w;
        float* o = out + (((size_t)(n * 81 + kk)) * HD + (i0 + r)) * WD + j0 + 4 * g;
        *(float4*)o = make_float4(acc[d][0], acc[d][1], acc[d][2], acc[d][3]);
    }
}

extern "C" void kernel_launch(void* const* d_in, const int* in_sizes, int n_in,
                              void* d_out, int out_size, void* d_ws, size_t ws_size,
                              hipStream_t stream) {
    const float* A = (const float*)d_in[0];
    const float* B = (const float*)d_in[1];
    float* out = (float*)d_out;
    // 256 B zero page for OOB/pad staging lanes (d_ws re-poisoned every launch).
    hipMemsetAsync(d_ws, 0, 256, stream);
    corr_vol_kernel<<<dim3(NB * 100), dim3(NTHREADS), 0, stream>>>(
        A, B, (const float*)d_ws, out);
}